// Round 12
// baseline (213.025 us; speedup 1.0000x reference)
//
#include <hip/hip_runtime.h>
#include <hip/hip_bf16.h>
#include <math.h>

typedef float f32x4 __attribute__((ext_vector_type(4)));
typedef __bf16 bf16x8 __attribute__((ext_vector_type(8)));
typedef _Float16 f16;
typedef _Float16 f16x4 __attribute__((ext_vector_type(4)));
typedef unsigned short ushort;

#define NROWS 8192
#define HID 256
#define NCOL 4096
#define NSTEPS 20

static __device__ inline float bf2f(ushort u) {
    union { unsigned int i; float f; } c; c.i = ((unsigned int)u) << 16; return c.f;
}
static __device__ inline ushort f2bf(float x) {
    __hip_bfloat16 h = __float2bfloat16(x);
    union { __hip_bfloat16 h; ushort u; } c; c.h = h; return c.u;
}
static __device__ inline void gload_lds16(const void* g, void* l) {
    __builtin_amdgcn_global_load_lds(
        (const __attribute__((address_space(1))) void*)g,
        (__attribute__((address_space(3))) void*)l, 16, 0, 0);
}

// ---------------------------------------------------------------- MLP layers 0+1 (+ fused kl_target)
__global__ __launch_bounds__(256) void mlp01_kernel(
    const float* __restrict__ x, const float* __restrict__ klb,
    const float* __restrict__ W0, const float* __restrict__ b0,
    const float* __restrict__ W1, const float* __restrict__ b1,
    const float* __restrict__ W2, const float* __restrict__ b2,
    const int* __restrict__ AL,
    ushort* __restrict__ t_ext, float* __restrict__ kt)
{
    __shared__ float xk[8][66];
    __shared__ float h0[8][HID];
    __shared__ float ktred[8][4];
    const int tid = threadIdx.x;
    const int lane = tid & 63, w = tid >> 6;
    const int r0 = blockIdx.x * 8;

    for (int f = tid; f < 8 * 64; f += 256) {
        int r = f >> 6, k = f & 63;
        xk[r][k] = x[(r0 + r) * 64 + k];
    }
    if (tid < 8) xk[tid][64] = klb[r0 + tid];
    __syncthreads();

    {
        float acc[8];
        float bb = b0[tid];
        #pragma unroll
        for (int r = 0; r < 8; r++) acc[r] = bb;
        for (int k = 0; k < 65; k++) {
            float w0 = W0[tid * 65 + k];
            #pragma unroll
            for (int r = 0; r < 8; r++) acc[r] += w0 * xk[r][k];
        }
        #pragma unroll
        for (int r = 0; r < 8; r++) h0[r][tid] = tanhf(acc[r]);
    }
    __syncthreads();
    {
        float acc[8];
        float bb = b1[tid];
        #pragma unroll
        for (int r = 0; r < 8; r++) acc[r] = bb;
        for (int k = 0; k < HID; k++) {
            float w1 = W1[tid * HID + k];
            #pragma unroll
            for (int r = 0; r < 8; r++) acc[r] += w1 * h0[r][k];
        }
        const float w2v = W2[tid];   // W2 row 0
        __syncthreads();
        #pragma unroll
        for (int r = 0; r < 8; r++) {
            float v = tanhf(acc[r]);
            ushort hi = f2bf(v);
            float lo = v - bf2f(hi);
            size_t base = (size_t)(r0 + r) * 512;
            t_ext[base + tid] = hi;
            t_ext[base + 256 + tid] = f2bf(lo);
            float p = v * w2v;
            #pragma unroll
            for (int off = 1; off < 64; off <<= 1) p += __shfl_xor(p, off);
            if (lane == 0) ktred[r][w] = p;
        }
        __syncthreads();
        if (tid < 8) {
            float accv = ktred[tid][0] + ktred[tid][1] + ktred[tid][2] + ktred[tid][3];
            float z = accv + b2[0] - logf((float)AL[0]);
            float sg = 1.0f / (1.0f + expf(-z));
            kt[r0 + tid] = sg * klb[r0 + tid] + 1e-6f;
        }
    }
}

// ---------------------------------------------------------------- W2 rows 1..4096 -> bf16 hi|lo [4096][512]
__global__ __launch_bounds__(256) void w2ext_kernel(const float* __restrict__ W2,
                                                    ushort* __restrict__ Bext)
{
    const int r = blockIdx.x, t = threadIdx.x;
    float v = W2[(size_t)(r + 1) * 256 + t];
    ushort hi = f2bf(v);
    float lo = v - bf2f(hi);
    Bext[(size_t)r * 512 + t] = hi;
    Bext[(size_t)r * 512 + 256 + t] = f2bf(lo);
}

// ---------------------------------------------------------------- FUSED layer-2 GEMM, coalesced epilogue
// laraw[r][c] = (t@W2^T + b2 + logb)[r][c] stored f16; partials[r][cblk] = (sum e, sum e*av)
// Epilogue: acc -> LDS (padded 132: uniform 2-way banks) -> row-linear pass with
// coalesced f32x4 logb loads + f16x4 laraw stores + 32-lane-group row reduction.
__global__ __launch_bounds__(256) void gemm2_fused(
    const ushort* __restrict__ Aext, const ushort* __restrict__ Bext,
    const float* __restrict__ b2, const float* __restrict__ logb,
    f16* __restrict__ laraw, float2* __restrict__ partials)
{
    __shared__ ushort As[128 * 64];
    __shared__ ushort Bs[128 * 64];
    __shared__ float epi[64][132];
    __shared__ float rowsum[128][2];
    const int tid = threadIdx.x;
    const int lane = tid & 63, w = tid >> 6;
    const int m0 = blockIdx.y * 128, c0 = blockIdx.x * 128;
    const int wm = w & 1, wn = w >> 1;

    f32x4 acc[4][4];
    #pragma unroll
    for (int i = 0; i < 4; i++)
        #pragma unroll
        for (int j = 0; j < 4; j++) acc[i][j] = (f32x4){0.f, 0.f, 0.f, 0.f};

    int sg_row[4], sg_c[4];
    #pragma unroll
    for (int s = 0; s < 4; s++) {
        int idx = (s * 4 + w) * 512 + lane * 8;
        int row = idx >> 6;
        int cp = (idx >> 3) & 7;
        sg_row[s] = row;
        sg_c[s] = cp ^ (row & 7);
    }

    for (int kt = 0; kt < 8; kt++) {
        const int k0 = kt * 64;
        #pragma unroll
        for (int s = 0; s < 4; s++) {
            gload_lds16(&Aext[(size_t)(m0 + sg_row[s]) * 512 + k0 + sg_c[s] * 8],
                        &As[(s * 4 + w) * 512]);
            gload_lds16(&Bext[(size_t)(c0 + sg_row[s]) * 512 + k0 + sg_c[s] * 8],
                        &Bs[(s * 4 + w) * 512]);
        }
        __syncthreads();
        #pragma unroll
        for (int kk = 0; kk < 2; kk++) {
            const int cA = kk * 4 + (lane >> 4);
            bf16x8 af[4], bfr[4];
            #pragma unroll
            for (int i = 0; i < 4; i++) {
                int mr = wm * 64 + i * 16 + (lane & 15);
                af[i] = *(const bf16x8*)&As[mr * 64 + ((cA ^ (mr & 7)) * 8)];
                int nr = wn * 64 + i * 16 + (lane & 15);
                bfr[i] = *(const bf16x8*)&Bs[nr * 64 + ((cA ^ (nr & 7)) * 8)];
            }
            #pragma unroll
            for (int i = 0; i < 4; i++)
                #pragma unroll
                for (int j = 0; j < 4; j++)
                    acc[i][j] = __builtin_amdgcn_mfma_f32_16x16x32_bf16(
                        af[i], bfr[j], acc[i][j], 0, 0, 0);
        }
        __syncthreads();
    }

    // ---- coalesced fused epilogue, two 64-row halves ----
    const int rsub = (lane >> 4) * 4;
    for (int h = 0; h < 2; h++) {
        if (wm == h) {
            #pragma unroll
            for (int i = 0; i < 4; i++)
                #pragma unroll
                for (int j = 0; j < 4; j++)
                    #pragma unroll
                    for (int q = 0; q < 4; q++)
                        epi[i * 16 + rsub + q][wn * 64 + (lane & 15) + j * 16] = acc[i][j][q];
        }
        __syncthreads();
        #pragma unroll
        for (int s = 0; s < 8; s++) {
            int idx = s * 256 + tid;        // f32x4 index within 64x128 half-tile
            int row = idx >> 5;             // 0..63
            int c4  = (idx & 31) * 4;       // col 0..124, step 4
            int rg = m0 + h * 64 + row;
            int cg = c0 + c4;
            f32x4 a4 = *(const f32x4*)&epi[row][c4];
            f32x4 b4 = *(const f32x4*)&logb[(size_t)rg * 4096 + cg];
            f32x4 bias4 = *(const f32x4*)&b2[1 + cg];
            f16x4 h4;
            float pe = 0.0f, pav = 0.0f;
            #pragma unroll
            for (int j = 0; j < 4; j++) {
                float av = a4[j] + bias4[j];
                float lr = av + b4[j];
                h4[j] = (f16)lr;
                float e = __expf(lr);
                pe += e;
                pav = fmaf(e, av, pav);
            }
            *(f16x4*)&laraw[(size_t)rg * 4096 + cg] = h4;
            #pragma unroll
            for (int m = 1; m < 32; m <<= 1) {
                pe  += __shfl_xor(pe, m);
                pav += __shfl_xor(pav, m);
            }
            if ((tid & 31) == 0) {
                rowsum[h * 64 + row][0] = pe;
                rowsum[h * 64 + row][1] = pav;
            }
        }
        __syncthreads();
    }
    if (tid < 128) {
        float2 pp;
        pp.x = rowsum[tid][0];
        pp.y = rowsum[tid][1];
        partials[(size_t)(m0 + tid) * 32 + blockIdx.x] = pp;
    }
}

// ---------------------------------------------------------------- FUSED solver: barrier-free fast path
__global__ __launch_bounds__(256) void solve_fused(
    float* __restrict__ out, const f16* __restrict__ laraw,
    const float2* __restrict__ partials, const float* __restrict__ logb,
    const float* __restrict__ ktarr)
{
    __shared__ float red[16];
    const int tid = threadIdx.x;
    const int lane = tid & 63, w = tid >> 6;
    const int r = blockIdx.x;

    float2 pv = partials[(size_t)r * 32 + (lane & 31)];
    float s = pv.x, sav = pv.y;
    #pragma unroll
    for (int off = 1; off < 32; off <<= 1) {
        s   += __shfl_xor(s, off);
        sav += __shfl_xor(sav, off);
    }
    const float k = ktarr[r];
    const float lns = __logf(s);
    const float inv = 1.0f / s;
    const float kl1 = fmaf(sav, inv, -lns);

    const f16* lrow = laraw + (size_t)r * 4096;
    float* orow = out + (size_t)r * 4096;

    if (k >= kl1) {   // fast path: alpha = 1, no barriers, pure stream
        #pragma unroll
        for (int c = 0; c < 4; c++) {
            f16x4 h4 = *(const f16x4*)&lrow[c * 1024 + tid * 4];
            f32x4 o;
            #pragma unroll
            for (int j = 0; j < 4; j++) o[j] = __expf((float)h4[j]) * inv;
            *(f32x4*)&orow[c * 1024 + tid * 4] = o;
        }
        if (tid == 0) {
            float d = kl1 - k;
            out[(size_t)NROWS * NCOL + r] = d * d;
        }
        return;
    }

    // ---------- slow path ----------
    float am[16], eb[16];
    float c2 = 0.0f, c3 = 0.0f, seb = 0.0f, samv = 0.0f;
    #pragma unroll
    for (int c = 0; c < 4; c++) {
        f16x4 h4 = *(const f16x4*)&lrow[c * 1024 + tid * 4];
        f32x4 b4 = *(const f32x4*)&logb[(size_t)r * 4096 + c * 1024 + tid * 4];
        #pragma unroll
        for (int j = 0; j < 4; j++) {
            int m = c * 4 + j;
            float lr = (float)h4[j], b = b4[j];
            float e = __expf(lr);
            float ebv = __expf(b);
            float a = fmaf(e, inv, -ebv);
            am[m] = a; eb[m] = ebv;
            c2 = fmaf(ebv, b, c2);
            c3 = fmaf(a, b, c3);
            seb += ebv;
            samv = fmaf(a, lr - b, samv);
        }
    }
    #pragma unroll
    for (int off = 1; off < 64; off <<= 1) {
        c2   += __shfl_xor(c2, off);
        c3   += __shfl_xor(c3, off);
        seb  += __shfl_xor(seb, off);
        samv += __shfl_xor(samv, off);
    }
    if (lane == 0) {
        red[w * 4 + 0] = c2;  red[w * 4 + 1] = c3;
        red[w * 4 + 2] = seb; red[w * 4 + 3] = samv;
    }
    __syncthreads();
    c2   = red[0] + red[4] + red[8]  + red[12];
    c3   = red[1] + red[5] + red[9]  + red[13];
    seb  = red[2] + red[6] + red[10] + red[14];
    samv = red[3] + red[7] + red[11] + red[15];

    const float C2 = c2;
    const float C3 = c3;
    const float C4 = (1.0f - seb) - C3;

    float skl = kl1, a_eval = 1.0f;
    float bot = 0.0f, top = 1.0f;
    float d1 = samv - lns * (1.0f - seb) + C4;
    float alpha = fminf(0.5f, fmaxf(1.0f / 16.0f,
                        1.0f + (k - kl1) / (d1 + 1e-12f)));

    for (int it = 1; it < NSTEPS; it++) {
        a_eval = alpha;
        float kacc = 0.0f, dacc = 0.0f;
        #pragma unroll
        for (int m = 0; m < 16; m++) {
            float xv = fmaf(alpha, am[m], eb[m]);
            float lx = __logf(xv);
            kacc = fmaf(xv, lx, kacc);
            dacc = fmaf(am[m], lx, dacc);
        }
        #pragma unroll
        for (int off = 1; off < 64; off <<= 1) {
            kacc += __shfl_xor(kacc, off);
            dacc += __shfl_xor(dacc, off);
        }
        __syncthreads();
        if (lane == 0) { red[w * 2 + 0] = kacc; red[w * 2 + 1] = dacc; }
        __syncthreads();
        kacc = red[0] + red[2] + red[4] + red[6];
        dacc = red[1] + red[3] + red[5] + red[7];

        float klc = kacc - C2 - alpha * C3;
        float dc  = dacc + C4;
        skl = klc;

        bot = (k >= klc) ? alpha : bot;
        top = (k <= klc) ? alpha : top;
        float delta = (k - klc) / (dc + 1e-12f);
        float lo = bot * (15.0f / 16.0f) + top * (1.0f / 16.0f);
        float hi = 0.5f * (bot + top);
        alpha = fminf(hi, fmaxf(lo, alpha + delta));
        if (top - bot < 1e-6f) break;
    }

    if (alpha != a_eval) {
        float kacc = 0.0f;
        #pragma unroll
        for (int m = 0; m < 16; m++) {
            float xv = fmaf(alpha, am[m], eb[m]);
            kacc = fmaf(xv, __logf(xv), kacc);
        }
        #pragma unroll
        for (int off = 1; off < 64; off <<= 1) kacc += __shfl_xor(kacc, off);
        __syncthreads();
        if (lane == 0) red[w] = kacc;
        __syncthreads();
        kacc = red[0] + red[1] + red[2] + red[3];
        skl = kacc - C2 - alpha * C3;
    }

    const float spx = fmaf(alpha, 1.0f - seb, seb);
    const float invs = 1.0f / spx;
    #pragma unroll
    for (int c = 0; c < 4; c++) {
        f32x4 o;
        #pragma unroll
        for (int j = 0; j < 4; j++)
            o[j] = fmaf(alpha, am[c * 4 + j], eb[c * 4 + j]) * invs;
        *(f32x4*)&orow[c * 1024 + tid * 4] = o;
    }
    if (tid == 0) {
        float d = skl - k;
        out[(size_t)NROWS * NCOL + r] = d * d;
    }
}

// ================================================================ fallback path (ws too small)
__global__ __launch_bounds__(256) void gemm2_mfma(
    const ushort* __restrict__ Aext, const ushort* __restrict__ Bext,
    const float* __restrict__ b2, float* __restrict__ h2out)
{
    __shared__ ushort As[128 * 64];
    __shared__ ushort Bs[128 * 64];
    const int tid = threadIdx.x;
    const int lane = tid & 63, w = tid >> 6;
    const int m0 = blockIdx.y * 128, c0 = blockIdx.x * 128;
    const int wm = w & 1, wn = w >> 1;

    f32x4 acc[4][4];
    #pragma unroll
    for (int i = 0; i < 4; i++)
        #pragma unroll
        for (int j = 0; j < 4; j++) acc[i][j] = (f32x4){0.f, 0.f, 0.f, 0.f};

    int sg_row[4], sg_c[4];
    #pragma unroll
    for (int s = 0; s < 4; s++) {
        int idx = (s * 4 + w) * 512 + lane * 8;
        int row = idx >> 6;
        int cp = (idx >> 3) & 7;
        sg_row[s] = row;
        sg_c[s] = cp ^ (row & 7);
    }
    for (int kt = 0; kt < 8; kt++) {
        const int k0 = kt * 64;
        #pragma unroll
        for (int s = 0; s < 4; s++) {
            gload_lds16(&Aext[(size_t)(m0 + sg_row[s]) * 512 + k0 + sg_c[s] * 8],
                        &As[(s * 4 + w) * 512]);
            gload_lds16(&Bext[(size_t)(c0 + sg_row[s]) * 512 + k0 + sg_c[s] * 8],
                        &Bs[(s * 4 + w) * 512]);
        }
        __syncthreads();
        #pragma unroll
        for (int kk = 0; kk < 2; kk++) {
            const int cA = kk * 4 + (lane >> 4);
            bf16x8 af[4], bfr[4];
            #pragma unroll
            for (int i = 0; i < 4; i++) {
                int mr = wm * 64 + i * 16 + (lane & 15);
                af[i] = *(const bf16x8*)&As[mr * 64 + ((cA ^ (mr & 7)) * 8)];
                int nr = wn * 64 + i * 16 + (lane & 15);
                bfr[i] = *(const bf16x8*)&Bs[nr * 64 + ((cA ^ (nr & 7)) * 8)];
            }
            #pragma unroll
            for (int i = 0; i < 4; i++)
                #pragma unroll
                for (int j = 0; j < 4; j++)
                    acc[i][j] = __builtin_amdgcn_mfma_f32_16x16x32_bf16(
                        af[i], bfr[j], acc[i][j], 0, 0, 0);
        }
        __syncthreads();
    }
    const int colb = c0 + wn * 64 + (lane & 15);
    #pragma unroll
    for (int j = 0; j < 4; j++) {
        float bias = b2[1 + colb + j * 16];
        #pragma unroll
        for (int i = 0; i < 4; i++) {
            int rr = m0 + wm * 64 + i * 16 + (lane >> 4) * 4;
            #pragma unroll
            for (int q = 0; q < 4; q++)
                h2out[(size_t)(rr + q) * 4096 + colb + j * 16] = acc[i][j][q] + bias;
        }
    }
}

__global__ __launch_bounds__(256) void solve_kernel(
    float* __restrict__ outbuf, const float* __restrict__ logb_g,
    const float* __restrict__ ktarr)
{
    __shared__ float red[16];
    const int tid = threadIdx.x;
    const int lane = tid & 63, w = tid >> 6;
    const int r = blockIdx.x;

    const float* rowA = outbuf + (size_t)r * 4096;
    const float* rowB = logb_g + (size_t)r * 4096;

    f32x4 av4[4], bv4[4];
    #pragma unroll
    for (int c = 0; c < 4; c++) {
        av4[c] = *(const f32x4*)&rowA[c * 1024 + tid * 4];
        bv4[c] = *(const f32x4*)&rowB[c * 1024 + tid * 4];
    }
    float e[16];
    float s = 0.0f, sav = 0.0f;
    #pragma unroll
    for (int c = 0; c < 4; c++)
        #pragma unroll
        for (int j = 0; j < 4; j++) {
            int m = c * 4 + j;
            e[m] = __expf(av4[c][j] + bv4[c][j]);
            s += e[m];
            sav = fmaf(e[m], av4[c][j], sav);
        }
    #pragma unroll
    for (int off = 1; off < 64; off <<= 1) {
        s   += __shfl_xor(s, off);
        sav += __shfl_xor(sav, off);
    }
    if (lane == 0) { red[w * 2] = s; red[w * 2 + 1] = sav; }
    __syncthreads();
    s   = red[0] + red[2] + red[4] + red[6];
    sav = red[1] + red[3] + red[5] + red[7];

    const float k = ktarr[r];
    const float lns = __logf(s);
    const float inv = 1.0f / s;
    const float kl1 = fmaf(sav, inv, -lns);
    float* orow = outbuf + (size_t)r * 4096;

    if (k >= kl1) {
        #pragma unroll
        for (int c = 0; c < 4; c++) {
            f32x4 o;
            #pragma unroll
            for (int j = 0; j < 4; j++) o[j] = e[c * 4 + j] * inv;
            *(f32x4*)&orow[c * 1024 + tid * 4] = o;
        }
        if (tid == 0) {
            float d = kl1 - k;
            outbuf[(size_t)NROWS * NCOL + r] = d * d;
        }
        return;
    }
    float eb[16];
    float c2 = 0.0f, c3 = 0.0f, seb = 0.0f, samv = 0.0f;
    #pragma unroll
    for (int c = 0; c < 4; c++)
        #pragma unroll
        for (int j = 0; j < 4; j++) {
            int m = c * 4 + j;
            float b = __expf(bv4[c][j]);
            eb[m] = b;
            float a = fmaf(e[m], inv, -b);
            e[m] = a;
            c2  = fmaf(b, bv4[c][j], c2);
            c3  = fmaf(a, bv4[c][j], c3);
            seb += b;
            samv = fmaf(a, av4[c][j], samv);
        }
    #pragma unroll
    for (int off = 1; off < 64; off <<= 1) {
        c2   += __shfl_xor(c2, off);
        c3   += __shfl_xor(c3, off);
        seb  += __shfl_xor(seb, off);
        samv += __shfl_xor(samv, off);
    }
    __syncthreads();
    if (lane == 0) {
        red[w * 4 + 0] = c2;  red[w * 4 + 1] = c3;
        red[w * 4 + 2] = seb; red[w * 4 + 3] = samv;
    }
    __syncthreads();
    c2   = red[0] + red[4] + red[8]  + red[12];
    c3   = red[1] + red[5] + red[9]  + red[13];
    seb  = red[2] + red[6] + red[10] + red[14];
    samv = red[3] + red[7] + red[11] + red[15];

    const float C2 = c2, C3 = c3;
    const float C4 = (1.0f - seb) - C3;
    float skl = kl1, a_eval = 1.0f;
    float bot = 0.0f, top = 1.0f;
    float d1 = samv - lns * (1.0f - seb) + C4;
    float alpha = fminf(0.5f, fmaxf(1.0f / 16.0f,
                        1.0f + (k - kl1) / (d1 + 1e-12f)));
    for (int it = 1; it < NSTEPS; it++) {
        a_eval = alpha;
        float kacc = 0.0f, dacc = 0.0f;
        #pragma unroll
        for (int m = 0; m < 16; m++) {
            float xv = fmaf(alpha, e[m], eb[m]);
            float lx = __logf(xv);
            kacc = fmaf(xv, lx, kacc);
            dacc = fmaf(e[m], lx, dacc);
        }
        #pragma unroll
        for (int off = 1; off < 64; off <<= 1) {
            kacc += __shfl_xor(kacc, off);
            dacc += __shfl_xor(dacc, off);
        }
        __syncthreads();
        if (lane == 0) { red[w * 2 + 0] = kacc; red[w * 2 + 1] = dacc; }
        __syncthreads();
        kacc = red[0] + red[2] + red[4] + red[6];
        dacc = red[1] + red[3] + red[5] + red[7];
        float klc = kacc - C2 - alpha * C3;
        float dc  = dacc + C4;
        skl = klc;
        bot = (k >= klc) ? alpha : bot;
        top = (k <= klc) ? alpha : top;
        float delta = (k - klc) / (dc + 1e-12f);
        float lo = bot * (15.0f / 16.0f) + top * (1.0f / 16.0f);
        float hi = 0.5f * (bot + top);
        alpha = fminf(hi, fmaxf(lo, alpha + delta));
        if (top - bot < 1e-6f) break;
    }
    if (alpha != a_eval) {
        float kacc = 0.0f;
        #pragma unroll
        for (int m = 0; m < 16; m++) {
            float xv = fmaf(alpha, e[m], eb[m]);
            kacc = fmaf(xv, __logf(xv), kacc);
        }
        #pragma unroll
        for (int off = 1; off < 64; off <<= 1) kacc += __shfl_xor(kacc, off);
        __syncthreads();
        if (lane == 0) red[w] = kacc;
        __syncthreads();
        kacc = red[0] + red[1] + red[2] + red[3];
        skl = kacc - C2 - alpha * C3;
    }
    const float spx = fmaf(alpha, 1.0f - seb, seb);
    const float invs = 1.0f / spx;
    #pragma unroll
    for (int c = 0; c < 4; c++) {
        f32x4 o;
        #pragma unroll
        for (int j = 0; j < 4; j++)
            o[j] = fmaf(alpha, e[c * 4 + j], eb[c * 4 + j]) * invs;
        *(f32x4*)&orow[c * 1024 + tid * 4] = o;
    }
    if (tid == 0) {
        float d = skl - k;
        outbuf[(size_t)NROWS * NCOL + r] = d * d;
    }
}

extern "C" void kernel_launch(void* const* d_in, const int* in_sizes, int n_in,
                              void* d_out, int out_size, void* d_ws, size_t ws_size,
                              hipStream_t stream)
{
    const float* x    = (const float*)d_in[0];
    const float* klb  = (const float*)d_in[1];
    const float* logb = (const float*)d_in[2];
    const float* W0   = (const float*)d_in[3];
    const float* b0   = (const float*)d_in[4];
    const float* W1   = (const float*)d_in[5];
    const float* b1   = (const float*)d_in[6];
    const float* W2   = (const float*)d_in[7];
    const float* b2   = (const float*)d_in[8];
    const int*   AL   = (const int*)d_in[9];
    float* out = (float*)d_out;

    const size_t MB = 1048576ull;
    char* p = (char*)d_ws;
    ushort* tws   = (ushort*)(p);            // Aext: 8 MB
    ushort* Bext  = (ushort*)(p + 8 * MB);   // 4 MB
    float*  kt    = (float*) (p + 12 * MB);  // 32 KB
    f16*    laraw = (f16*)   (p + 16 * MB);  // 64 MB
    float2* part  = (float2*)(p + 80 * MB);  // 2 MB
    const size_t NEED = 82 * MB;

    hipLaunchKernelGGL(mlp01_kernel, dim3(1024), dim3(256), 0, stream,
                       x, klb, W0, b0, W1, b1, W2, b2, AL, tws, kt);
    hipLaunchKernelGGL(w2ext_kernel, dim3(4096), dim3(256), 0, stream, W2, Bext);

    if (ws_size >= NEED) {
        hipLaunchKernelGGL(gemm2_fused, dim3(32, 64), dim3(256), 0, stream,
                           tws, Bext, b2, logb, laraw, part);
        hipLaunchKernelGGL(solve_fused, dim3(8192), dim3(256), 0, stream,
                           out, laraw, part, logb, kt);
    } else {
        hipLaunchKernelGGL(gemm2_mfma, dim3(32, 64), dim3(256), 0, stream,
                           tws, Bext, b2, out);
        hipLaunchKernelGGL(solve_kernel, dim3(8192), dim3(256), 0, stream,
                           out, logb, kt);
    }
}

// Round 13
// 211.418 us; speedup vs baseline: 1.0076x; 1.0076x over previous
//
#include <hip/hip_runtime.h>
#include <hip/hip_bf16.h>
#include <math.h>

typedef float f32x4 __attribute__((ext_vector_type(4)));
typedef __bf16 bf16x8 __attribute__((ext_vector_type(8)));
typedef _Float16 f16;
typedef _Float16 f16x4 __attribute__((ext_vector_type(4)));
typedef unsigned short ushort;

#define NROWS 8192
#define HID 256
#define NCOL 4096
#define NSTEPS 20

static __device__ inline float bf2f(ushort u) {
    union { unsigned int i; float f; } c; c.i = ((unsigned int)u) << 16; return c.f;
}
static __device__ inline ushort f2bf(float x) {
    __hip_bfloat16 h = __float2bfloat16(x);
    union { __hip_bfloat16 h; ushort u; } c; c.h = h; return c.u;
}
static __device__ inline void gload_lds16(const void* g, void* l) {
    __builtin_amdgcn_global_load_lds(
        (const __attribute__((address_space(1))) void*)g,
        (__attribute__((address_space(3))) void*)l, 16, 0, 0);
}

// ---------------------------------------------------------------- MLP layers 0+1 (+ fused kl_target)
__global__ __launch_bounds__(256) void mlp01_kernel(
    const float* __restrict__ x, const float* __restrict__ klb,
    const float* __restrict__ W0, const float* __restrict__ b0,
    const float* __restrict__ W1, const float* __restrict__ b1,
    const float* __restrict__ W2, const float* __restrict__ b2,
    const int* __restrict__ AL,
    ushort* __restrict__ t_ext, float* __restrict__ kt)
{
    __shared__ float xk[8][66];
    __shared__ float h0[8][HID];
    __shared__ float ktred[8][4];
    const int tid = threadIdx.x;
    const int lane = tid & 63, w = tid >> 6;
    const int r0 = blockIdx.x * 8;

    for (int f = tid; f < 8 * 64; f += 256) {
        int r = f >> 6, k = f & 63;
        xk[r][k] = x[(r0 + r) * 64 + k];
    }
    if (tid < 8) xk[tid][64] = klb[r0 + tid];
    __syncthreads();

    {
        float acc[8];
        float bb = b0[tid];
        #pragma unroll
        for (int r = 0; r < 8; r++) acc[r] = bb;
        for (int k = 0; k < 65; k++) {
            float w0 = W0[tid * 65 + k];
            #pragma unroll
            for (int r = 0; r < 8; r++) acc[r] += w0 * xk[r][k];
        }
        #pragma unroll
        for (int r = 0; r < 8; r++) h0[r][tid] = tanhf(acc[r]);
    }
    __syncthreads();
    {
        float acc[8];
        float bb = b1[tid];
        #pragma unroll
        for (int r = 0; r < 8; r++) acc[r] = bb;
        for (int k = 0; k < HID; k++) {
            float w1 = W1[tid * HID + k];
            #pragma unroll
            for (int r = 0; r < 8; r++) acc[r] += w1 * h0[r][k];
        }
        const float w2v = W2[tid];   // W2 row 0
        __syncthreads();
        #pragma unroll
        for (int r = 0; r < 8; r++) {
            float v = tanhf(acc[r]);
            ushort hi = f2bf(v);
            float lo = v - bf2f(hi);
            size_t base = (size_t)(r0 + r) * 512;
            t_ext[base + tid] = hi;
            t_ext[base + 256 + tid] = f2bf(lo);
            float p = v * w2v;
            #pragma unroll
            for (int off = 1; off < 64; off <<= 1) p += __shfl_xor(p, off);
            if (lane == 0) ktred[r][w] = p;
        }
        __syncthreads();
        if (tid < 8) {
            float accv = ktred[tid][0] + ktred[tid][1] + ktred[tid][2] + ktred[tid][3];
            float z = accv + b2[0] - logf((float)AL[0]);
            float sg = 1.0f / (1.0f + expf(-z));
            kt[r0 + tid] = sg * klb[r0 + tid] + 1e-6f;
        }
    }
}

// ---------------------------------------------------------------- W2 rows 1..4096 -> bf16 hi|lo; b2s = b2[1:] copy
__global__ __launch_bounds__(256) void w2ext_kernel(const float* __restrict__ W2,
                                                    const float* __restrict__ b2,
                                                    ushort* __restrict__ Bext,
                                                    float* __restrict__ b2s)
{
    const int r = blockIdx.x, t = threadIdx.x;
    float v = W2[(size_t)(r + 1) * 256 + t];
    ushort hi = f2bf(v);
    float lo = v - bf2f(hi);
    Bext[(size_t)r * 512 + t] = hi;
    Bext[(size_t)r * 512 + 256 + t] = f2bf(lo);
    if (t == 0) b2s[r] = b2[r + 1];
}

// ---------------------------------------------------------------- FUSED layer-2 GEMM, transposed-MFMA epilogue
// mfma(bfr, af, acc) gives C^T fragments: lane holds C[row=lane&15][4 consecutive
// cols]. Epilogue: vectorized f32x4 logb loads + f16x4 laraw stores, no extra LDS.
// partials[r][cb] = (sum e, sum e*av) over 64-col chunk cb, e = exp(av + logb).
__global__ __launch_bounds__(256) void gemm2_fused(
    const ushort* __restrict__ Aext, const ushort* __restrict__ Bext,
    const float* __restrict__ b2s, const float* __restrict__ logb,
    f16* __restrict__ laraw, float2* __restrict__ partials)
{
    __shared__ ushort As[128 * 64];
    __shared__ ushort Bs[128 * 64];
    const int tid = threadIdx.x;
    const int lane = tid & 63, w = tid >> 6;
    const int m0 = blockIdx.y * 128, c0 = blockIdx.x * 128;
    const int wm = w & 1, wn = w >> 1;

    f32x4 acc[4][4];
    #pragma unroll
    for (int i = 0; i < 4; i++)
        #pragma unroll
        for (int j = 0; j < 4; j++) acc[i][j] = (f32x4){0.f, 0.f, 0.f, 0.f};

    int sg_row[4], sg_c[4];
    #pragma unroll
    for (int s = 0; s < 4; s++) {
        int idx = (s * 4 + w) * 512 + lane * 8;
        int row = idx >> 6;
        int cp = (idx >> 3) & 7;
        sg_row[s] = row;
        sg_c[s] = cp ^ (row & 7);
    }

    for (int kt = 0; kt < 8; kt++) {
        const int k0 = kt * 64;
        #pragma unroll
        for (int s = 0; s < 4; s++) {
            gload_lds16(&Aext[(size_t)(m0 + sg_row[s]) * 512 + k0 + sg_c[s] * 8],
                        &As[(s * 4 + w) * 512]);
            gload_lds16(&Bext[(size_t)(c0 + sg_row[s]) * 512 + k0 + sg_c[s] * 8],
                        &Bs[(s * 4 + w) * 512]);
        }
        __syncthreads();
        #pragma unroll
        for (int kk = 0; kk < 2; kk++) {
            const int cA = kk * 4 + (lane >> 4);
            bf16x8 af[4], bfr[4];
            #pragma unroll
            for (int i = 0; i < 4; i++) {
                int mr = wm * 64 + i * 16 + (lane & 15);
                af[i] = *(const bf16x8*)&As[mr * 64 + ((cA ^ (mr & 7)) * 8)];
                int nr = wn * 64 + i * 16 + (lane & 15);
                bfr[i] = *(const bf16x8*)&Bs[nr * 64 + ((cA ^ (nr & 7)) * 8)];
            }
            // swapped operands -> transposed C fragments
            #pragma unroll
            for (int i = 0; i < 4; i++)
                #pragma unroll
                for (int j = 0; j < 4; j++)
                    acc[i][j] = __builtin_amdgcn_mfma_f32_16x16x32_bf16(
                        bfr[j], af[i], acc[i][j], 0, 0, 0);
        }
        __syncthreads();
    }

    // ---- fused epilogue: lane owns rows (lane&15), 4 consecutive cols ----
    const int rloc = lane & 15;
    const int cq4 = (lane >> 4) * 4;
    float pe[4], pav[4];
    #pragma unroll
    for (int i = 0; i < 4; i++) { pe[i] = 0.0f; pav[i] = 0.0f; }

    #pragma unroll
    for (int j = 0; j < 4; j++) {
        const int cg = c0 + wn * 64 + j * 16 + cq4;
        f32x4 bias4 = *(const f32x4*)&b2s[cg];
        #pragma unroll
        for (int i = 0; i < 4; i++) {
            const int rg = m0 + wm * 64 + i * 16 + rloc;
            f32x4 b4 = *(const f32x4*)&logb[(size_t)rg * 4096 + cg];
            f16x4 h4;
            #pragma unroll
            for (int q = 0; q < 4; q++) {
                float av = acc[i][j][q] + bias4[q];
                float lr = av + b4[q];
                h4[q] = (f16)lr;
                float e = __expf(lr);
                pe[i] += e;
                pav[i] = fmaf(e, av, pav[i]);
            }
            *(f16x4*)&laraw[(size_t)rg * 4096 + cg] = h4;
        }
    }
    // reduce over the 4 col-groups (lane bits 4,5); rows stay lane-local
    #pragma unroll
    for (int i = 0; i < 4; i++) {
        pe[i]  += __shfl_xor(pe[i], 16);  pe[i]  += __shfl_xor(pe[i], 32);
        pav[i] += __shfl_xor(pav[i], 16); pav[i] += __shfl_xor(pav[i], 32);
    }
    if (lane < 16) {
        const int cb = blockIdx.x * 2 + wn;
        #pragma unroll
        for (int i = 0; i < 4; i++) {
            float2 pp;
            pp.x = pe[i];
            pp.y = pav[i];
            partials[(size_t)(m0 + wm * 64 + i * 16 + lane) * 64 + cb] = pp;
        }
    }
}

// ---------------------------------------------------------------- FUSED solver: barrier-free fast path
__global__ __launch_bounds__(256) void solve_fused(
    float* __restrict__ out, const f16* __restrict__ laraw,
    const float2* __restrict__ partials, const float* __restrict__ logb,
    const float* __restrict__ ktarr)
{
    __shared__ float red[16];
    const int tid = threadIdx.x;
    const int lane = tid & 63, w = tid >> 6;
    const int r = blockIdx.x;

    float2 pv = partials[(size_t)r * 64 + lane];
    float s = pv.x, sav = pv.y;
    #pragma unroll
    for (int off = 1; off < 64; off <<= 1) {
        s   += __shfl_xor(s, off);
        sav += __shfl_xor(sav, off);
    }
    const float k = ktarr[r];
    const float lns = __logf(s);
    const float inv = 1.0f / s;
    const float kl1 = fmaf(sav, inv, -lns);

    const f16* lrow = laraw + (size_t)r * 4096;
    float* orow = out + (size_t)r * 4096;

    if (k >= kl1) {   // fast path: alpha = 1, no barriers, pure stream
        #pragma unroll
        for (int c = 0; c < 4; c++) {
            f16x4 h4 = *(const f16x4*)&lrow[c * 1024 + tid * 4];
            f32x4 o;
            #pragma unroll
            for (int j = 0; j < 4; j++) o[j] = __expf((float)h4[j]) * inv;
            *(f32x4*)&orow[c * 1024 + tid * 4] = o;
        }
        if (tid == 0) {
            float d = kl1 - k;
            out[(size_t)NROWS * NCOL + r] = d * d;
        }
        return;
    }

    // ---------- slow path ----------
    float am[16], eb[16];
    float c2 = 0.0f, c3 = 0.0f, seb = 0.0f, samv = 0.0f;
    #pragma unroll
    for (int c = 0; c < 4; c++) {
        f16x4 h4 = *(const f16x4*)&lrow[c * 1024 + tid * 4];
        f32x4 b4 = *(const f32x4*)&logb[(size_t)r * 4096 + c * 1024 + tid * 4];
        #pragma unroll
        for (int j = 0; j < 4; j++) {
            int m = c * 4 + j;
            float lr = (float)h4[j], b = b4[j];
            float e = __expf(lr);
            float ebv = __expf(b);
            float a = fmaf(e, inv, -ebv);
            am[m] = a; eb[m] = ebv;
            c2 = fmaf(ebv, b, c2);
            c3 = fmaf(a, b, c3);
            seb += ebv;
            samv = fmaf(a, lr - b, samv);
        }
    }
    #pragma unroll
    for (int off = 1; off < 64; off <<= 1) {
        c2   += __shfl_xor(c2, off);
        c3   += __shfl_xor(c3, off);
        seb  += __shfl_xor(seb, off);
        samv += __shfl_xor(samv, off);
    }
    if (lane == 0) {
        red[w * 4 + 0] = c2;  red[w * 4 + 1] = c3;
        red[w * 4 + 2] = seb; red[w * 4 + 3] = samv;
    }
    __syncthreads();
    c2   = red[0] + red[4] + red[8]  + red[12];
    c3   = red[1] + red[5] + red[9]  + red[13];
    seb  = red[2] + red[6] + red[10] + red[14];
    samv = red[3] + red[7] + red[11] + red[15];

    const float C2 = c2;
    const float C3 = c3;
    const float C4 = (1.0f - seb) - C3;

    float skl = kl1, a_eval = 1.0f;
    float bot = 0.0f, top = 1.0f;
    float d1 = samv - lns * (1.0f - seb) + C4;
    float alpha = fminf(0.5f, fmaxf(1.0f / 16.0f,
                        1.0f + (k - kl1) / (d1 + 1e-12f)));

    for (int it = 1; it < NSTEPS; it++) {
        a_eval = alpha;
        float kacc = 0.0f, dacc = 0.0f;
        #pragma unroll
        for (int m = 0; m < 16; m++) {
            float xv = fmaf(alpha, am[m], eb[m]);
            float lx = __logf(xv);
            kacc = fmaf(xv, lx, kacc);
            dacc = fmaf(am[m], lx, dacc);
        }
        #pragma unroll
        for (int off = 1; off < 64; off <<= 1) {
            kacc += __shfl_xor(kacc, off);
            dacc += __shfl_xor(dacc, off);
        }
        __syncthreads();
        if (lane == 0) { red[w * 2 + 0] = kacc; red[w * 2 + 1] = dacc; }
        __syncthreads();
        kacc = red[0] + red[2] + red[4] + red[6];
        dacc = red[1] + red[3] + red[5] + red[7];

        float klc = kacc - C2 - alpha * C3;
        float dc  = dacc + C4;
        skl = klc;

        bot = (k >= klc) ? alpha : bot;
        top = (k <= klc) ? alpha : top;
        float delta = (k - klc) / (dc + 1e-12f);
        float lo = bot * (15.0f / 16.0f) + top * (1.0f / 16.0f);
        float hi = 0.5f * (bot + top);
        alpha = fminf(hi, fmaxf(lo, alpha + delta));
        if (top - bot < 1e-6f) break;
    }

    if (alpha != a_eval) {
        float kacc = 0.0f;
        #pragma unroll
        for (int m = 0; m < 16; m++) {
            float xv = fmaf(alpha, am[m], eb[m]);
            kacc = fmaf(xv, __logf(xv), kacc);
        }
        #pragma unroll
        for (int off = 1; off < 64; off <<= 1) kacc += __shfl_xor(kacc, off);
        __syncthreads();
        if (lane == 0) red[w] = kacc;
        __syncthreads();
        kacc = red[0] + red[1] + red[2] + red[3];
        skl = kacc - C2 - alpha * C3;
    }

    const float spx = fmaf(alpha, 1.0f - seb, seb);
    const float invs = 1.0f / spx;
    #pragma unroll
    for (int c = 0; c < 4; c++) {
        f32x4 o;
        #pragma unroll
        for (int j = 0; j < 4; j++)
            o[j] = fmaf(alpha, am[c * 4 + j], eb[c * 4 + j]) * invs;
        *(f32x4*)&orow[c * 1024 + tid * 4] = o;
    }
    if (tid == 0) {
        float d = skl - k;
        out[(size_t)NROWS * NCOL + r] = d * d;
    }
}

// ================================================================ fallback path (ws too small)
__global__ __launch_bounds__(256) void gemm2_mfma(
    const ushort* __restrict__ Aext, const ushort* __restrict__ Bext,
    const float* __restrict__ b2, float* __restrict__ h2out)
{
    __shared__ ushort As[128 * 64];
    __shared__ ushort Bs[128 * 64];
    const int tid = threadIdx.x;
    const int lane = tid & 63, w = tid >> 6;
    const int m0 = blockIdx.y * 128, c0 = blockIdx.x * 128;
    const int wm = w & 1, wn = w >> 1;

    f32x4 acc[4][4];
    #pragma unroll
    for (int i = 0; i < 4; i++)
        #pragma unroll
        for (int j = 0; j < 4; j++) acc[i][j] = (f32x4){0.f, 0.f, 0.f, 0.f};

    int sg_row[4], sg_c[4];
    #pragma unroll
    for (int s = 0; s < 4; s++) {
        int idx = (s * 4 + w) * 512 + lane * 8;
        int row = idx >> 6;
        int cp = (idx >> 3) & 7;
        sg_row[s] = row;
        sg_c[s] = cp ^ (row & 7);
    }
    for (int kt = 0; kt < 8; kt++) {
        const int k0 = kt * 64;
        #pragma unroll
        for (int s = 0; s < 4; s++) {
            gload_lds16(&Aext[(size_t)(m0 + sg_row[s]) * 512 + k0 + sg_c[s] * 8],
                        &As[(s * 4 + w) * 512]);
            gload_lds16(&Bext[(size_t)(c0 + sg_row[s]) * 512 + k0 + sg_c[s] * 8],
                        &Bs[(s * 4 + w) * 512]);
        }
        __syncthreads();
        #pragma unroll
        for (int kk = 0; kk < 2; kk++) {
            const int cA = kk * 4 + (lane >> 4);
            bf16x8 af[4], bfr[4];
            #pragma unroll
            for (int i = 0; i < 4; i++) {
                int mr = wm * 64 + i * 16 + (lane & 15);
                af[i] = *(const bf16x8*)&As[mr * 64 + ((cA ^ (mr & 7)) * 8)];
                int nr = wn * 64 + i * 16 + (lane & 15);
                bfr[i] = *(const bf16x8*)&Bs[nr * 64 + ((cA ^ (nr & 7)) * 8)];
            }
            #pragma unroll
            for (int i = 0; i < 4; i++)
                #pragma unroll
                for (int j = 0; j < 4; j++)
                    acc[i][j] = __builtin_amdgcn_mfma_f32_16x16x32_bf16(
                        af[i], bfr[j], acc[i][j], 0, 0, 0);
        }
        __syncthreads();
    }
    const int colb = c0 + wn * 64 + (lane & 15);
    #pragma unroll
    for (int j = 0; j < 4; j++) {
        float bias = b2[1 + colb + j * 16];
        #pragma unroll
        for (int i = 0; i < 4; i++) {
            int rr = m0 + wm * 64 + i * 16 + (lane >> 4) * 4;
            #pragma unroll
            for (int q = 0; q < 4; q++)
                h2out[(size_t)(rr + q) * 4096 + colb + j * 16] = acc[i][j][q] + bias;
        }
    }
}

__global__ __launch_bounds__(256) void solve_kernel(
    float* __restrict__ outbuf, const float* __restrict__ logb_g,
    const float* __restrict__ ktarr)
{
    __shared__ float red[16];
    const int tid = threadIdx.x;
    const int lane = tid & 63, w = tid >> 6;
    const int r = blockIdx.x;

    const float* rowA = outbuf + (size_t)r * 4096;
    const float* rowB = logb_g + (size_t)r * 4096;

    f32x4 av4[4], bv4[4];
    #pragma unroll
    for (int c = 0; c < 4; c++) {
        av4[c] = *(const f32x4*)&rowA[c * 1024 + tid * 4];
        bv4[c] = *(const f32x4*)&rowB[c * 1024 + tid * 4];
    }
    float e[16];
    float s = 0.0f, sav = 0.0f;
    #pragma unroll
    for (int c = 0; c < 4; c++)
        #pragma unroll
        for (int j = 0; j < 4; j++) {
            int m = c * 4 + j;
            e[m] = __expf(av4[c][j] + bv4[c][j]);
            s += e[m];
            sav = fmaf(e[m], av4[c][j], sav);
        }
    #pragma unroll
    for (int off = 1; off < 64; off <<= 1) {
        s   += __shfl_xor(s, off);
        sav += __shfl_xor(sav, off);
    }
    if (lane == 0) { red[w * 2] = s; red[w * 2 + 1] = sav; }
    __syncthreads();
    s   = red[0] + red[2] + red[4] + red[6];
    sav = red[1] + red[3] + red[5] + red[7];

    const float k = ktarr[r];
    const float lns = __logf(s);
    const float inv = 1.0f / s;
    const float kl1 = fmaf(sav, inv, -lns);
    float* orow = outbuf + (size_t)r * 4096;

    if (k >= kl1) {
        #pragma unroll
        for (int c = 0; c < 4; c++) {
            f32x4 o;
            #pragma unroll
            for (int j = 0; j < 4; j++) o[j] = e[c * 4 + j] * inv;
            *(f32x4*)&orow[c * 1024 + tid * 4] = o;
        }
        if (tid == 0) {
            float d = kl1 - k;
            outbuf[(size_t)NROWS * NCOL + r] = d * d;
        }
        return;
    }
    float eb[16];
    float c2 = 0.0f, c3 = 0.0f, seb = 0.0f, samv = 0.0f;
    #pragma unroll
    for (int c = 0; c < 4; c++)
        #pragma unroll
        for (int j = 0; j < 4; j++) {
            int m = c * 4 + j;
            float b = __expf(bv4[c][j]);
            eb[m] = b;
            float a = fmaf(e[m], inv, -b);
            e[m] = a;
            c2  = fmaf(b, bv4[c][j], c2);
            c3  = fmaf(a, bv4[c][j], c3);
            seb += b;
            samv = fmaf(a, av4[c][j], samv);
        }
    #pragma unroll
    for (int off = 1; off < 64; off <<= 1) {
        c2   += __shfl_xor(c2, off);
        c3   += __shfl_xor(c3, off);
        seb  += __shfl_xor(seb, off);
        samv += __shfl_xor(samv, off);
    }
    __syncthreads();
    if (lane == 0) {
        red[w * 4 + 0] = c2;  red[w * 4 + 1] = c3;
        red[w * 4 + 2] = seb; red[w * 4 + 3] = samv;
    }
    __syncthreads();
    c2   = red[0] + red[4] + red[8]  + red[12];
    c3   = red[1] + red[5] + red[9]  + red[13];
    seb  = red[2] + red[6] + red[10] + red[14];
    samv = red[3] + red[7] + red[11] + red[15];

    const float C2 = c2, C3 = c3;
    const float C4 = (1.0f - seb) - C3;
    float skl = kl1, a_eval = 1.0f;
    float bot = 0.0f, top = 1.0f;
    float d1 = samv - lns * (1.0f - seb) + C4;
    float alpha = fminf(0.5f, fmaxf(1.0f / 16.0f,
                        1.0f + (k - kl1) / (d1 + 1e-12f)));
    for (int it = 1; it < NSTEPS; it++) {
        a_eval = alpha;
        float kacc = 0.0f, dacc = 0.0f;
        #pragma unroll
        for (int m = 0; m < 16; m++) {
            float xv = fmaf(alpha, e[m], eb[m]);
            float lx = __logf(xv);
            kacc = fmaf(xv, lx, kacc);
            dacc = fmaf(e[m], lx, dacc);
        }
        #pragma unroll
        for (int off = 1; off < 64; off <<= 1) {
            kacc += __shfl_xor(kacc, off);
            dacc += __shfl_xor(dacc, off);
        }
        __syncthreads();
        if (lane == 0) { red[w * 2 + 0] = kacc; red[w * 2 + 1] = dacc; }
        __syncthreads();
        kacc = red[0] + red[2] + red[4] + red[6];
        dacc = red[1] + red[3] + red[5] + red[7];
        float klc = kacc - C2 - alpha * C3;
        float dc  = dacc + C4;
        skl = klc;
        bot = (k >= klc) ? alpha : bot;
        top = (k <= klc) ? alpha : top;
        float delta = (k - klc) / (dc + 1e-12f);
        float lo = bot * (15.0f / 16.0f) + top * (1.0f / 16.0f);
        float hi = 0.5f * (bot + top);
        alpha = fminf(hi, fmaxf(lo, alpha + delta));
        if (top - bot < 1e-6f) break;
    }
    if (alpha != a_eval) {
        float kacc = 0.0f;
        #pragma unroll
        for (int m = 0; m < 16; m++) {
            float xv = fmaf(alpha, e[m], eb[m]);
            kacc = fmaf(xv, __logf(xv), kacc);
        }
        #pragma unroll
        for (int off = 1; off < 64; off <<= 1) kacc += __shfl_xor(kacc, off);
        __syncthreads();
        if (lane == 0) red[w] = kacc;
        __syncthreads();
        kacc = red[0] + red[1] + red[2] + red[3];
        skl = kacc - C2 - alpha * C3;
    }
    const float spx = fmaf(alpha, 1.0f - seb, seb);
    const float invs = 1.0f / spx;
    #pragma unroll
    for (int c = 0; c < 4; c++) {
        f32x4 o;
        #pragma unroll
        for (int j = 0; j < 4; j++)
            o[j] = fmaf(alpha, e[c * 4 + j], eb[c * 4 + j]) * invs;
        *(f32x4*)&orow[c * 1024 + tid * 4] = o;
    }
    if (tid == 0) {
        float d = skl - k;
        outbuf[(size_t)NROWS * NCOL + r] = d * d;
    }
}

extern "C" void kernel_launch(void* const* d_in, const int* in_sizes, int n_in,
                              void* d_out, int out_size, void* d_ws, size_t ws_size,
                              hipStream_t stream)
{
    const float* x    = (const float*)d_in[0];
    const float* klb  = (const float*)d_in[1];
    const float* logb = (const float*)d_in[2];
    const float* W0   = (const float*)d_in[3];
    const float* b0   = (const float*)d_in[4];
    const float* W1   = (const float*)d_in[5];
    const float* b1   = (const float*)d_in[6];
    const float* W2   = (const float*)d_in[7];
    const float* b2   = (const float*)d_in[8];
    const int*   AL   = (const int*)d_in[9];
    float* out = (float*)d_out;

    const size_t MB = 1048576ull;
    char* p = (char*)d_ws;
    ushort* tws   = (ushort*)(p);                  // Aext: 8 MB
    ushort* Bext  = (ushort*)(p + 8 * MB);         // 4 MB
    float*  kt    = (float*) (p + 12 * MB);        // 32 KB
    float*  b2s   = (float*) (p + 12 * MB + 65536);// 16 KB
    f16*    laraw = (f16*)   (p + 16 * MB);        // 64 MB
    float2* part  = (float2*)(p + 80 * MB);        // 4 MB ([8192][64] float2)
    const size_t NEED = 84 * MB;

    hipLaunchKernelGGL(mlp01_kernel, dim3(1024), dim3(256), 0, stream,
                       x, klb, W0, b0, W1, b1, W2, b2, AL, tws, kt);
    hipLaunchKernelGGL(w2ext_kernel, dim3(4096), dim3(256), 0, stream, W2, b2, Bext, b2s);

    if (ws_size >= NEED) {
        hipLaunchKernelGGL(gemm2_fused, dim3(32, 64), dim3(256), 0, stream,
                           tws, Bext, b2s, logb, laraw, part);
        hipLaunchKernelGGL(solve_fused, dim3(8192), dim3(256), 0, stream,
                           out, laraw, part, logb, kt);
    } else {
        hipLaunchKernelGGL(gemm2_mfma, dim3(32, 64), dim3(256), 0, stream,
                           tws, Bext, b2, out);
        hipLaunchKernelGGL(solve_kernel, dim3(8192), dim3(256), 0, stream,
                           out, logb, kt);
    }
}

// Round 14
// 172.815 us; speedup vs baseline: 1.2327x; 1.2234x over previous
//
#include <hip/hip_runtime.h>
#include <hip/hip_bf16.h>
#include <math.h>

typedef float f32x4 __attribute__((ext_vector_type(4)));
typedef __bf16 bf16x8 __attribute__((ext_vector_type(8)));
typedef _Float16 f16;
typedef _Float16 f16x8 __attribute__((ext_vector_type(8)));
typedef unsigned short ushort;

#define NROWS 8192
#define HID 256
#define NCOL 4096
#define NSTEPS 20

static __device__ inline float bf2f(ushort u) {
    union { unsigned int i; float f; } c; c.i = ((unsigned int)u) << 16; return c.f;
}
static __device__ inline ushort f2bf(float x) {
    __hip_bfloat16 h = __float2bfloat16(x);
    union { __hip_bfloat16 h; ushort u; } c; c.h = h; return c.u;
}
static __device__ inline float fast_tanh(float x) {
    float e = __expf(2.0f * x);
    return 1.0f - 2.0f / (e + 1.0f);
}
static __device__ inline void gload_lds16(const void* g, void* l) {
    __builtin_amdgcn_global_load_lds(
        (const __attribute__((address_space(1))) void*)g,
        (__attribute__((address_space(3))) void*)l, 16, 0, 0);
}

// ---------------------------------------------------------------- MLP layers 0+1 (+ fused kl_target)
__global__ __launch_bounds__(256) void mlp01_kernel(
    const float* __restrict__ x, const float* __restrict__ klb,
    const float* __restrict__ W0, const float* __restrict__ b0,
    const float* __restrict__ W1, const float* __restrict__ b1,
    const float* __restrict__ W2, const float* __restrict__ b2,
    const int* __restrict__ AL,
    ushort* __restrict__ t_ext, float* __restrict__ kt)
{
    __shared__ float xk[8][66];
    __shared__ float h0[8][HID];
    __shared__ float ktred[8][4];
    const int tid = threadIdx.x;
    const int lane = tid & 63, w = tid >> 6;
    const int r0 = blockIdx.x * 8;

    for (int f = tid; f < 8 * 64; f += 256) {
        int r = f >> 6, k = f & 63;
        xk[r][k] = x[(r0 + r) * 64 + k];
    }
    if (tid < 8) xk[tid][64] = klb[r0 + tid];
    __syncthreads();

    {
        float acc[8];
        float bb = b0[tid];
        #pragma unroll
        for (int r = 0; r < 8; r++) acc[r] = bb;
        for (int k = 0; k < 65; k++) {
            float w0 = W0[tid * 65 + k];
            #pragma unroll
            for (int r = 0; r < 8; r++) acc[r] += w0 * xk[r][k];
        }
        #pragma unroll
        for (int r = 0; r < 8; r++) h0[r][tid] = fast_tanh(acc[r]);
    }
    __syncthreads();
    {
        float acc[8];
        float bb = b1[tid];
        #pragma unroll
        for (int r = 0; r < 8; r++) acc[r] = bb;
        for (int k = 0; k < HID; k++) {
            float w1 = W1[tid * HID + k];
            #pragma unroll
            for (int r = 0; r < 8; r++) acc[r] += w1 * h0[r][k];
        }
        const float w2v = W2[tid];   // W2 row 0
        __syncthreads();
        #pragma unroll
        for (int r = 0; r < 8; r++) {
            float v = fast_tanh(acc[r]);
            ushort hi = f2bf(v);
            float lo = v - bf2f(hi);
            size_t base = (size_t)(r0 + r) * 512;
            t_ext[base + tid] = hi;
            t_ext[base + 256 + tid] = f2bf(lo);
            float p = v * w2v;
            #pragma unroll
            for (int off = 1; off < 64; off <<= 1) p += __shfl_xor(p, off);
            if (lane == 0) ktred[r][w] = p;
        }
        __syncthreads();
        if (tid < 8) {
            float accv = ktred[tid][0] + ktred[tid][1] + ktred[tid][2] + ktred[tid][3];
            float z = accv + b2[0] - logf((float)AL[0]);
            float sg = 1.0f / (1.0f + expf(-z));
            kt[r0 + tid] = sg * klb[r0 + tid] + 1e-6f;
        }
    }
}

// ---------------------------------------------------------------- W2 rows 1..4096 -> bf16 hi|lo; b2s = b2[1:]
__global__ __launch_bounds__(256) void w2ext_kernel(const float* __restrict__ W2,
                                                    const float* __restrict__ b2,
                                                    ushort* __restrict__ Bext,
                                                    float* __restrict__ b2s)
{
    const int r = blockIdx.x, t = threadIdx.x;
    float v = W2[(size_t)(r + 1) * 256 + t];
    ushort hi = f2bf(v);
    float lo = v - bf2f(hi);
    Bext[(size_t)r * 512 + t] = hi;
    Bext[(size_t)r * 512 + 256 + t] = f2bf(lo);
    if (t == 0) b2s[r] = b2[r + 1];
}

// ---------------------------------------------------------------- layer-2 GEMM (split-bf16 MFMA), f16 logit out
__global__ __launch_bounds__(256) void gemm2_mfma(
    const ushort* __restrict__ Aext, const ushort* __restrict__ Bext,
    const float* __restrict__ b2s, f16* __restrict__ h2f)
{
    __shared__ ushort As[128 * 64];
    __shared__ ushort Bs[128 * 64];
    const int tid = threadIdx.x;
    const int lane = tid & 63, w = tid >> 6;
    const int m0 = blockIdx.y * 128, c0 = blockIdx.x * 128;
    const int wm = w & 1, wn = w >> 1;

    f32x4 acc[4][4];
    #pragma unroll
    for (int i = 0; i < 4; i++)
        #pragma unroll
        for (int j = 0; j < 4; j++) acc[i][j] = (f32x4){0.f, 0.f, 0.f, 0.f};

    int sg_row[4], sg_c[4];
    #pragma unroll
    for (int s = 0; s < 4; s++) {
        int idx = (s * 4 + w) * 512 + lane * 8;
        int row = idx >> 6;
        int cp = (idx >> 3) & 7;
        sg_row[s] = row;
        sg_c[s] = cp ^ (row & 7);
    }

    for (int kt = 0; kt < 8; kt++) {
        const int k0 = kt * 64;
        #pragma unroll
        for (int s = 0; s < 4; s++) {
            gload_lds16(&Aext[(size_t)(m0 + sg_row[s]) * 512 + k0 + sg_c[s] * 8],
                        &As[(s * 4 + w) * 512]);
            gload_lds16(&Bext[(size_t)(c0 + sg_row[s]) * 512 + k0 + sg_c[s] * 8],
                        &Bs[(s * 4 + w) * 512]);
        }
        __syncthreads();
        #pragma unroll
        for (int kk = 0; kk < 2; kk++) {
            const int cA = kk * 4 + (lane >> 4);
            bf16x8 af[4], bfr[4];
            #pragma unroll
            for (int i = 0; i < 4; i++) {
                int mr = wm * 64 + i * 16 + (lane & 15);
                af[i] = *(const bf16x8*)&As[mr * 64 + ((cA ^ (mr & 7)) * 8)];
                int nr = wn * 64 + i * 16 + (lane & 15);
                bfr[i] = *(const bf16x8*)&Bs[nr * 64 + ((cA ^ (nr & 7)) * 8)];
            }
            #pragma unroll
            for (int i = 0; i < 4; i++)
                #pragma unroll
                for (int j = 0; j < 4; j++)
                    acc[i][j] = __builtin_amdgcn_mfma_f32_16x16x32_bf16(
                        af[i], bfr[j], acc[i][j], 0, 0, 0);
        }
        __syncthreads();
    }

    const int colb = c0 + wn * 64 + (lane & 15);
    #pragma unroll
    for (int j = 0; j < 4; j++) {
        float bias = b2s[colb + j * 16];
        #pragma unroll
        for (int i = 0; i < 4; i++) {
            int rr = m0 + wm * 64 + i * 16 + (lane >> 4) * 4;
            #pragma unroll
            for (int q = 0; q < 4; q++)
                h2f[(size_t)(rr + q) * 4096 + colb + j * 16] = (f16)(acc[i][j][q] + bias);
        }
    }
}

// ---------------------------------------------------------------- solver: EIGHT WAVES PER ROW (512 thr)
// 8 elems/thread; f16 logits; analytic fast path; log-free final for collapsed rows.
__global__ __launch_bounds__(512) void solve512(
    float* __restrict__ out, const f16* __restrict__ h2f,
    const float* __restrict__ logb, const float* __restrict__ ktarr)
{
    __shared__ float red[32];
    const int tid = threadIdx.x;          // 0..511
    const int lane = tid & 63, w = tid >> 6;
    const int r = blockIdx.x;

    const f16* hrow = h2f + (size_t)r * 4096;
    const float* brow = logb + (size_t)r * 4096;

    f16x8 h8 = *(const f16x8*)&hrow[tid * 8];
    f32x4 bq0 = *(const f32x4*)&brow[tid * 8];
    f32x4 bq1 = *(const f32x4*)&brow[tid * 8 + 4];

    float av[8], bv[8], e[8];
    float s = 0.0f, sav = 0.0f;
    #pragma unroll
    for (int j = 0; j < 8; j++) {
        av[j] = (float)h8[j];
        bv[j] = (j < 4) ? bq0[j & 3] : bq1[j & 3];
        e[j] = __expf(av[j] + bv[j]);
        s += e[j];
        sav = fmaf(e[j], av[j], sav);
    }
    #pragma unroll
    for (int off = 1; off < 64; off <<= 1) {
        s   += __shfl_xor(s, off);
        sav += __shfl_xor(sav, off);
    }
    if (lane == 0) { red[w * 2] = s; red[w * 2 + 1] = sav; }
    __syncthreads();
    s = 0.0f; sav = 0.0f;
    #pragma unroll
    for (int i = 0; i < 8; i++) { s += red[i * 2]; sav += red[i * 2 + 1]; }

    const float k = ktarr[r];
    const float lns = __logf(s);
    const float inv = 1.0f / s;
    const float kl1 = fmaf(sav, inv, -lns);       // KL(a||b) at alpha=1

    float* orow = out + (size_t)r * 4096;

    if (k >= kl1) {  // fast path: alpha=1 (block-uniform), no more barriers
        f32x4 o0, o1;
        #pragma unroll
        for (int j = 0; j < 4; j++) { o0[j] = e[j] * inv; o1[j] = e[j + 4] * inv; }
        *(f32x4*)&orow[tid * 8] = o0;
        *(f32x4*)&orow[tid * 8 + 4] = o1;
        if (tid == 0) {
            float d = kl1 - k;
            out[(size_t)NROWS * NCOL + r] = d * d;
        }
        return;
    }

    // ---------- slow path (~few % of rows) ----------
    float am[8], eb[8];
    float c2 = 0.0f, c3 = 0.0f, seb = 0.0f, samv = 0.0f;
    #pragma unroll
    for (int j = 0; j < 8; j++) {
        float b = __expf(bv[j]);
        eb[j] = b;
        float a = fmaf(e[j], inv, -b);    // amb = ea - eb
        am[j] = a;
        c2   = fmaf(b, bv[j], c2);        // sum eb*lb
        c3   = fmaf(a, bv[j], c3);        // sum amb*lb
        seb += b;
        samv = fmaf(a, av[j], samv);      // sum amb*av
    }
    #pragma unroll
    for (int off = 1; off < 64; off <<= 1) {
        c2   += __shfl_xor(c2, off);
        c3   += __shfl_xor(c3, off);
        seb  += __shfl_xor(seb, off);
        samv += __shfl_xor(samv, off);
    }
    __syncthreads();
    if (lane == 0) {
        red[w * 4 + 0] = c2;  red[w * 4 + 1] = c3;
        red[w * 4 + 2] = seb; red[w * 4 + 3] = samv;
    }
    __syncthreads();
    c2 = 0.0f; c3 = 0.0f; seb = 0.0f; samv = 0.0f;
    #pragma unroll
    for (int i = 0; i < 8; i++) {
        c2   += red[i * 4 + 0];
        c3   += red[i * 4 + 1];
        seb  += red[i * 4 + 2];
        samv += red[i * 4 + 3];
    }

    const float C2 = c2;
    const float C3 = c3;
    const float C4 = (1.0f - seb) - C3;

    // analytic first Newton step at alpha=1: d1 = samv - lns*(1-seb) + (1-seb)
    float skl = kl1, a_eval = 1.0f;
    float bot = 0.0f, top = 1.0f;
    float d1 = samv - lns * (1.0f - seb) + (1.0f - seb);
    float alpha = fminf(0.5f, fmaxf(1.0f / 16.0f,
                        1.0f + (k - kl1) / (d1 + 1e-12f)));

    for (int it = 1; it < NSTEPS; it++) {
        a_eval = alpha;
        float kacc = 0.0f, dacc = 0.0f;
        #pragma unroll
        for (int j = 0; j < 8; j++) {
            float xv = fmaf(alpha, am[j], eb[j]);
            float lx = __logf(xv);
            kacc = fmaf(xv, lx, kacc);
            dacc = fmaf(am[j], lx, dacc);
        }
        #pragma unroll
        for (int off = 1; off < 64; off <<= 1) {
            kacc += __shfl_xor(kacc, off);
            dacc += __shfl_xor(dacc, off);
        }
        __syncthreads();
        if (lane == 0) { red[w * 2 + 0] = kacc; red[w * 2 + 1] = dacc; }
        __syncthreads();
        kacc = 0.0f; dacc = 0.0f;
        #pragma unroll
        for (int i = 0; i < 8; i++) { kacc += red[i * 2]; dacc += red[i * 2 + 1]; }

        float klc = kacc - C2 - alpha * C3;
        float dc  = dacc + C4;
        skl = klc;

        bot = (k >= klc) ? alpha : bot;
        top = (k <= klc) ? alpha : top;
        float delta = (k - klc) / (dc + 1e-12f);
        float lo = bot * (15.0f / 16.0f) + top * (1.0f / 16.0f);
        float hi = 0.5f * (bot + top);
        alpha = fminf(hi, fmaxf(lo, alpha + delta));
        if (top - bot < 1e-6f) break;
    }

    if (alpha != a_eval) {
        float kacc = 0.0f;
        #pragma unroll
        for (int j = 0; j < 8; j++) {
            float xv = fmaf(alpha, am[j], eb[j]);
            kacc = fmaf(xv, __logf(xv), kacc);
        }
        #pragma unroll
        for (int off = 1; off < 64; off <<= 1) kacc += __shfl_xor(kacc, off);
        __syncthreads();
        if (lane == 0) red[w] = kacc;
        __syncthreads();
        kacc = 0.0f;
        #pragma unroll
        for (int i = 0; i < 8; i++) kacc += red[i];
        skl = kacc - C2 - alpha * C3;
    }

    const float spx = fmaf(alpha, 1.0f - seb, seb);
    const float invs = 1.0f / spx;
    f32x4 o0, o1;
    #pragma unroll
    for (int j = 0; j < 4; j++) {
        o0[j] = fmaf(alpha, am[j], eb[j]) * invs;
        o1[j] = fmaf(alpha, am[j + 4], eb[j + 4]) * invs;
    }
    *(f32x4*)&orow[tid * 8] = o0;
    *(f32x4*)&orow[tid * 8 + 4] = o1;
    if (tid == 0) {
        float d = skl - k;
        out[(size_t)NROWS * NCOL + r] = d * d;
    }
}

extern "C" void kernel_launch(void* const* d_in, const int* in_sizes, int n_in,
                              void* d_out, int out_size, void* d_ws, size_t ws_size,
                              hipStream_t stream)
{
    const float* x    = (const float*)d_in[0];
    const float* klb  = (const float*)d_in[1];
    const float* logb = (const float*)d_in[2];
    const float* W0   = (const float*)d_in[3];
    const float* b0   = (const float*)d_in[4];
    const float* W1   = (const float*)d_in[5];
    const float* b1   = (const float*)d_in[6];
    const float* W2   = (const float*)d_in[7];
    const float* b2   = (const float*)d_in[8];
    const int*   AL   = (const int*)d_in[9];
    float* out = (float*)d_out;

    const size_t MB = 1048576ull;
    char* p = (char*)d_ws;
    ushort* tws  = (ushort*)(p);                   // Aext: 8 MB
    ushort* Bext = (ushort*)(p + 8 * MB);          // 4 MB
    float*  kt   = (float*) (p + 12 * MB);         // 32 KB
    float*  b2s  = (float*) (p + 12 * MB + 65536); // 16 KB
    f16*    h2f  = (f16*)   (p + 16 * MB);         // 64 MB

    hipLaunchKernelGGL(mlp01_kernel, dim3(1024), dim3(256), 0, stream,
                       x, klb, W0, b0, W1, b1, W2, b2, AL, tws, kt);
    hipLaunchKernelGGL(w2ext_kernel, dim3(4096), dim3(256), 0, stream, W2, b2, Bext, b2s);
    hipLaunchKernelGGL(gemm2_mfma, dim3(32, 64), dim3(256), 0, stream, tws, Bext, b2s, h2f);
    hipLaunchKernelGGL(solve512, dim3(8192), dim3(512), 0, stream, out, h2f, logb, kt);
}

// Round 15
// 171.987 us; speedup vs baseline: 1.2386x; 1.0048x over previous
//
#include <hip/hip_runtime.h>
#include <hip/hip_bf16.h>
#include <math.h>

typedef float f32x4 __attribute__((ext_vector_type(4)));
typedef __bf16 bf16x8 __attribute__((ext_vector_type(8)));
typedef _Float16 f16;
typedef _Float16 f16x8 __attribute__((ext_vector_type(8)));
typedef unsigned short ushort;

#define NROWS 8192
#define HID 256
#define NCOL 4096
#define NSTEPS 20

static __device__ inline float bf2f(ushort u) {
    union { unsigned int i; float f; } c; c.i = ((unsigned int)u) << 16; return c.f;
}
static __device__ inline ushort f2bf(float x) {
    __hip_bfloat16 h = __float2bfloat16(x);
    union { __hip_bfloat16 h; ushort u; } c; c.h = h; return c.u;
}
static __device__ inline float fast_tanh(float x) {
    float e = __expf(2.0f * x);
    return 1.0f - 2.0f / (e + 1.0f);
}
static __device__ inline void gload_lds16(const void* g, void* l) {
    __builtin_amdgcn_global_load_lds(
        (const __attribute__((address_space(1))) void*)g,
        (__attribute__((address_space(3))) void*)l, 16, 0, 0);
}

// ---------------------------------------------------------------- prep: W2 -> bf16 hi|lo, b2s, W0t, W1t
__global__ __launch_bounds__(256) void prep_kernel(
    const float* __restrict__ W2, const float* __restrict__ b2,
    const float* __restrict__ W0, const float* __restrict__ W1,
    ushort* __restrict__ Bext, float* __restrict__ b2s,
    float* __restrict__ W0t, float* __restrict__ W1t)
{
    const int r = blockIdx.x, t = threadIdx.x;
    float v = W2[(size_t)(r + 1) * 256 + t];
    ushort hi = f2bf(v);
    float lo = v - bf2f(hi);
    Bext[(size_t)r * 512 + t] = hi;
    Bext[(size_t)r * 512 + 256 + t] = f2bf(lo);
    if (t == 0) b2s[r] = b2[r + 1];
    if (r < 256) W1t[r * 256 + t] = W1[t * 256 + r];      // W1t[k][n] = W1[n][k]
    if (r < 65)  W0t[r * 256 + t] = W0[t * 65 + r];       // W0t[k][n] = W0[n][k]
}

// ---------------------------------------------------------------- MLP layers 0+1 (+ fused kl_target)
// Transposed coalesced weight access; 16 rows/block.
__global__ __launch_bounds__(256) void mlp01_kernel(
    const float* __restrict__ x, const float* __restrict__ klb,
    const float* __restrict__ W0t, const float* __restrict__ b0,
    const float* __restrict__ W1t, const float* __restrict__ b1,
    const float* __restrict__ W2, const float* __restrict__ b2,
    const int* __restrict__ AL,
    ushort* __restrict__ t_ext, float* __restrict__ kt)
{
    __shared__ float xk[16][66];
    __shared__ float h0[16][HID];
    __shared__ float ktred[16][4];
    const int tid = threadIdx.x;
    const int lane = tid & 63, w = tid >> 6;
    const int r0 = blockIdx.x * 16;

    for (int f = tid; f < 16 * 64; f += 256) {
        int r = f >> 6, k = f & 63;
        xk[r][k] = x[(size_t)(r0 + r) * 64 + k];
    }
    if (tid < 16) xk[tid][64] = klb[r0 + tid];
    __syncthreads();

    {
        float acc[16];
        float bb = b0[tid];
        #pragma unroll
        for (int r = 0; r < 16; r++) acc[r] = bb;
        for (int k = 0; k < 65; k++) {
            float wv = W0t[k * 256 + tid];      // coalesced
            #pragma unroll
            for (int r = 0; r < 16; r++) acc[r] = fmaf(wv, xk[r][k], acc[r]);
        }
        #pragma unroll
        for (int r = 0; r < 16; r++) h0[r][tid] = fast_tanh(acc[r]);
    }
    __syncthreads();
    {
        float acc[16];
        float bb = b1[tid];
        #pragma unroll
        for (int r = 0; r < 16; r++) acc[r] = bb;
        for (int k = 0; k < HID; k++) {
            float wv = W1t[k * 256 + tid];      // coalesced
            #pragma unroll
            for (int r = 0; r < 16; r++) acc[r] = fmaf(wv, h0[r][k], acc[r]);
        }
        const float w2v = W2[tid];   // W2 row 0
        __syncthreads();
        #pragma unroll
        for (int r = 0; r < 16; r++) {
            float v = fast_tanh(acc[r]);
            ushort hi = f2bf(v);
            float lo = v - bf2f(hi);
            size_t base = (size_t)(r0 + r) * 512;
            t_ext[base + tid] = hi;
            t_ext[base + 256 + tid] = f2bf(lo);
            float p = v * w2v;
            #pragma unroll
            for (int off = 1; off < 64; off <<= 1) p += __shfl_xor(p, off);
            if (lane == 0) ktred[r][w] = p;
        }
        __syncthreads();
        if (tid < 16) {
            float accv = ktred[tid][0] + ktred[tid][1] + ktred[tid][2] + ktred[tid][3];
            float z = accv + b2[0] - logf((float)AL[0]);
            float sg = 1.0f / (1.0f + expf(-z));
            kt[r0 + tid] = sg * klb[r0 + tid] + 1e-6f;
        }
    }
}

// ---------------------------------------------------------------- layer-2 GEMM (split-bf16 MFMA), f16 logit out
__global__ __launch_bounds__(256) void gemm2_mfma(
    const ushort* __restrict__ Aext, const ushort* __restrict__ Bext,
    const float* __restrict__ b2s, f16* __restrict__ h2f)
{
    __shared__ ushort As[128 * 64];
    __shared__ ushort Bs[128 * 64];
    const int tid = threadIdx.x;
    const int lane = tid & 63, w = tid >> 6;
    const int m0 = blockIdx.y * 128, c0 = blockIdx.x * 128;
    const int wm = w & 1, wn = w >> 1;

    f32x4 acc[4][4];
    #pragma unroll
    for (int i = 0; i < 4; i++)
        #pragma unroll
        for (int j = 0; j < 4; j++) acc[i][j] = (f32x4){0.f, 0.f, 0.f, 0.f};

    int sg_row[4], sg_c[4];
    #pragma unroll
    for (int s = 0; s < 4; s++) {
        int idx = (s * 4 + w) * 512 + lane * 8;
        int row = idx >> 6;
        int cp = (idx >> 3) & 7;
        sg_row[s] = row;
        sg_c[s] = cp ^ (row & 7);
    }

    for (int kt = 0; kt < 8; kt++) {
        const int k0 = kt * 64;
        #pragma unroll
        for (int s = 0; s < 4; s++) {
            gload_lds16(&Aext[(size_t)(m0 + sg_row[s]) * 512 + k0 + sg_c[s] * 8],
                        &As[(s * 4 + w) * 512]);
            gload_lds16(&Bext[(size_t)(c0 + sg_row[s]) * 512 + k0 + sg_c[s] * 8],
                        &Bs[(s * 4 + w) * 512]);
        }
        __syncthreads();
        #pragma unroll
        for (int kk = 0; kk < 2; kk++) {
            const int cA = kk * 4 + (lane >> 4);
            bf16x8 af[4], bfr[4];
            #pragma unroll
            for (int i = 0; i < 4; i++) {
                int mr = wm * 64 + i * 16 + (lane & 15);
                af[i] = *(const bf16x8*)&As[mr * 64 + ((cA ^ (mr & 7)) * 8)];
                int nr = wn * 64 + i * 16 + (lane & 15);
                bfr[i] = *(const bf16x8*)&Bs[nr * 64 + ((cA ^ (nr & 7)) * 8)];
            }
            #pragma unroll
            for (int i = 0; i < 4; i++)
                #pragma unroll
                for (int j = 0; j < 4; j++)
                    acc[i][j] = __builtin_amdgcn_mfma_f32_16x16x32_bf16(
                        af[i], bfr[j], acc[i][j], 0, 0, 0);
        }
        __syncthreads();
    }

    const int colb = c0 + wn * 64 + (lane & 15);
    #pragma unroll
    for (int j = 0; j < 4; j++) {
        float bias = b2s[colb + j * 16];
        #pragma unroll
        for (int i = 0; i < 4; i++) {
            int rr = m0 + wm * 64 + i * 16 + (lane >> 4) * 4;
            #pragma unroll
            for (int q = 0; q < 4; q++)
                h2f[(size_t)(rr + q) * 4096 + colb + j * 16] = (f16)(acc[i][j][q] + bias);
        }
    }
}

// ---------------------------------------------------------------- solver: EIGHT WAVES PER ROW (512 thr)
__global__ __launch_bounds__(512) void solve512(
    float* __restrict__ out, const f16* __restrict__ h2f,
    const float* __restrict__ logb, const float* __restrict__ ktarr)
{
    __shared__ float red[32];
    const int tid = threadIdx.x;          // 0..511
    const int lane = tid & 63, w = tid >> 6;
    const int r = blockIdx.x;

    const f16* hrow = h2f + (size_t)r * 4096;
    const float* brow = logb + (size_t)r * 4096;

    f16x8 h8 = *(const f16x8*)&hrow[tid * 8];
    f32x4 bq0 = *(const f32x4*)&brow[tid * 8];
    f32x4 bq1 = *(const f32x4*)&brow[tid * 8 + 4];

    float av[8], bv[8], e[8];
    float s = 0.0f, sav = 0.0f;
    #pragma unroll
    for (int j = 0; j < 8; j++) {
        av[j] = (float)h8[j];
        bv[j] = (j < 4) ? bq0[j & 3] : bq1[j & 3];
        e[j] = __expf(av[j] + bv[j]);
        s += e[j];
        sav = fmaf(e[j], av[j], sav);
    }
    #pragma unroll
    for (int off = 1; off < 64; off <<= 1) {
        s   += __shfl_xor(s, off);
        sav += __shfl_xor(sav, off);
    }
    if (lane == 0) { red[w * 2] = s; red[w * 2 + 1] = sav; }
    __syncthreads();
    s = 0.0f; sav = 0.0f;
    #pragma unroll
    for (int i = 0; i < 8; i++) { s += red[i * 2]; sav += red[i * 2 + 1]; }

    const float k = ktarr[r];
    const float lns = __logf(s);
    const float inv = 1.0f / s;
    const float kl1 = fmaf(sav, inv, -lns);       // KL(a||b) at alpha=1

    float* orow = out + (size_t)r * 4096;

    if (k >= kl1) {  // fast path: alpha=1 (block-uniform), no more barriers
        f32x4 o0, o1;
        #pragma unroll
        for (int j = 0; j < 4; j++) { o0[j] = e[j] * inv; o1[j] = e[j + 4] * inv; }
        *(f32x4*)&orow[tid * 8] = o0;
        *(f32x4*)&orow[tid * 8 + 4] = o1;
        if (tid == 0) {
            float d = kl1 - k;
            out[(size_t)NROWS * NCOL + r] = d * d;
        }
        return;
    }

    // ---------- slow path (~few % of rows) ----------
    float am[8], eb[8];
    float c2 = 0.0f, c3 = 0.0f, seb = 0.0f, samv = 0.0f;
    #pragma unroll
    for (int j = 0; j < 8; j++) {
        float b = __expf(bv[j]);
        eb[j] = b;
        float a = fmaf(e[j], inv, -b);    // amb = ea - eb
        am[j] = a;
        c2   = fmaf(b, bv[j], c2);        // sum eb*lb
        c3   = fmaf(a, bv[j], c3);        // sum amb*lb
        seb += b;
        samv = fmaf(a, av[j], samv);      // sum amb*av
    }
    #pragma unroll
    for (int off = 1; off < 64; off <<= 1) {
        c2   += __shfl_xor(c2, off);
        c3   += __shfl_xor(c3, off);
        seb  += __shfl_xor(seb, off);
        samv += __shfl_xor(samv, off);
    }
    __syncthreads();
    if (lane == 0) {
        red[w * 4 + 0] = c2;  red[w * 4 + 1] = c3;
        red[w * 4 + 2] = seb; red[w * 4 + 3] = samv;
    }
    __syncthreads();
    c2 = 0.0f; c3 = 0.0f; seb = 0.0f; samv = 0.0f;
    #pragma unroll
    for (int i = 0; i < 8; i++) {
        c2   += red[i * 4 + 0];
        c3   += red[i * 4 + 1];
        seb  += red[i * 4 + 2];
        samv += red[i * 4 + 3];
    }

    const float C2 = c2;
    const float C3 = c3;
    const float C4 = (1.0f - seb) - C3;

    float skl = kl1, a_eval = 1.0f;
    float bot = 0.0f, top = 1.0f;
    float d1 = samv - lns * (1.0f - seb) + (1.0f - seb);
    float alpha = fminf(0.5f, fmaxf(1.0f / 16.0f,
                        1.0f + (k - kl1) / (d1 + 1e-12f)));

    for (int it = 1; it < NSTEPS; it++) {
        a_eval = alpha;
        float kacc = 0.0f, dacc = 0.0f;
        #pragma unroll
        for (int j = 0; j < 8; j++) {
            float xv = fmaf(alpha, am[j], eb[j]);
            float lx = __logf(xv);
            kacc = fmaf(xv, lx, kacc);
            dacc = fmaf(am[j], lx, dacc);
        }
        #pragma unroll
        for (int off = 1; off < 64; off <<= 1) {
            kacc += __shfl_xor(kacc, off);
            dacc += __shfl_xor(dacc, off);
        }
        __syncthreads();
        if (lane == 0) { red[w * 2 + 0] = kacc; red[w * 2 + 1] = dacc; }
        __syncthreads();
        kacc = 0.0f; dacc = 0.0f;
        #pragma unroll
        for (int i = 0; i < 8; i++) { kacc += red[i * 2]; dacc += red[i * 2 + 1]; }

        float klc = kacc - C2 - alpha * C3;
        float dc  = dacc + C4;
        skl = klc;

        bot = (k >= klc) ? alpha : bot;
        top = (k <= klc) ? alpha : top;
        float delta = (k - klc) / (dc + 1e-12f);
        float lo = bot * (15.0f / 16.0f) + top * (1.0f / 16.0f);
        float hi = 0.5f * (bot + top);
        alpha = fminf(hi, fmaxf(lo, alpha + delta));
        if (top - bot < 1e-6f) break;
    }

    if (alpha != a_eval) {
        float kacc = 0.0f;
        #pragma unroll
        for (int j = 0; j < 8; j++) {
            float xv = fmaf(alpha, am[j], eb[j]);
            kacc = fmaf(xv, __logf(xv), kacc);
        }
        #pragma unroll
        for (int off = 1; off < 64; off <<= 1) kacc += __shfl_xor(kacc, off);
        __syncthreads();
        if (lane == 0) red[w] = kacc;
        __syncthreads();
        kacc = 0.0f;
        #pragma unroll
        for (int i = 0; i < 8; i++) kacc += red[i];
        skl = kacc - C2 - alpha * C3;
    }

    const float spx = fmaf(alpha, 1.0f - seb, seb);
    const float invs = 1.0f / spx;
    f32x4 o0, o1;
    #pragma unroll
    for (int j = 0; j < 4; j++) {
        o0[j] = fmaf(alpha, am[j], eb[j]) * invs;
        o1[j] = fmaf(alpha, am[j + 4], eb[j + 4]) * invs;
    }
    *(f32x4*)&orow[tid * 8] = o0;
    *(f32x4*)&orow[tid * 8 + 4] = o1;
    if (tid == 0) {
        float d = skl - k;
        out[(size_t)NROWS * NCOL + r] = d * d;
    }
}

extern "C" void kernel_launch(void* const* d_in, const int* in_sizes, int n_in,
                              void* d_out, int out_size, void* d_ws, size_t ws_size,
                              hipStream_t stream)
{
    const float* x    = (const float*)d_in[0];
    const float* klb  = (const float*)d_in[1];
    const float* logb = (const float*)d_in[2];
    const float* W0   = (const float*)d_in[3];
    const float* b0   = (const float*)d_in[4];
    const float* W1   = (const float*)d_in[5];
    const float* b1   = (const float*)d_in[6];
    const float* W2   = (const float*)d_in[7];
    const float* b2   = (const float*)d_in[8];
    const int*   AL   = (const int*)d_in[9];
    float* out = (float*)d_out;

    const size_t MB = 1048576ull;
    const size_t KB = 1024ull;
    char* p = (char*)d_ws;
    ushort* tws  = (ushort*)(p);                    // Aext: 8 MB
    ushort* Bext = (ushort*)(p + 8 * MB);           // 4 MB
    float*  kt   = (float*) (p + 12 * MB);          // 32 KB
    float*  b2s  = (float*) (p + 12 * MB + 64 * KB);  // 16 KB
    float*  W0t  = (float*) (p + 12 * MB + 128 * KB); // 65*256*4 = 66.6 KB
    float*  W1t  = (float*) (p + 12 * MB + 256 * KB); // 256 KB
    f16*    h2f  = (f16*)   (p + 16 * MB);          // 64 MB

    hipLaunchKernelGGL(prep_kernel, dim3(4096), dim3(256), 0, stream,
                       W2, b2, W0, W1, Bext, b2s, W0t, W1t);
    hipLaunchKernelGGL(mlp01_kernel, dim3(512), dim3(256), 0, stream,
                       x, klb, W0t, b0, W1t, b1, W2, b2, AL, tws, kt);
    hipLaunchKernelGGL(gemm2_mfma, dim3(32, 64), dim3(256), 0, stream, tws, Bext, b2s, h2f);
    hipLaunchKernelGGL(solve512, dim3(8192), dim3(512), 0, stream, out, h2f, logb, kt);
}